// Round 1
// baseline (534.787 us; speedup 1.0000x reference)
//
#include <hip/hip_runtime.h>
#include <stdint.h>

#define M_DIM 8192
#define N_DIM 4096
#define K_DIM 4096
#define NUM_VQ (N_DIM * K_DIM / 8)     // 2,097,152 VQ blocks
#define NUM_X  (M_DIM * K_DIM)         // 33,554,432 x elements
#define VQ_BLOCKS (NUM_VQ / 256)       // 8192
#define CVT_BLOCKS (NUM_X / 8 / 256)   // 16384

#define DEPTH  4                       // LDS ring stages
#define TILES  (K_DIM / 32)            // 128
#define ROUNDS (TILES / DEPTH)         // 32

#define AS1 __attribute__((address_space(1)))
#define AS3 __attribute__((address_space(3)))

typedef __attribute__((ext_vector_type(4))) float f32x4;
typedef __attribute__((ext_vector_type(8))) short bf16x8;
typedef unsigned short u16;

__device__ inline unsigned short f2bf(float f) {
    union { float f; unsigned int i; } v; v.f = f;
    unsigned int x = v.i;
    return (unsigned short)((x + 0x7FFFu + ((x >> 16) & 1u)) >> 16);  // RNE
}

// ---------------------------------------------------------------------------
// Fused prep: blocks [0, VQ_BLOCKS) decompress VQ + fold scale (with inline
// per-wave int64-vs-int32 label probe); blocks [VQ_BLOCKS, ...) convert x.
// ---------------------------------------------------------------------------
__global__ void prep(const int* __restrict__ labels,
                     const float* __restrict__ centroids,
                     const float* __restrict__ scale,
                     const float* __restrict__ x,
                     u16* __restrict__ Ws, u16* __restrict__ Xb) {
    int b = blockIdx.x;
    if (b < VQ_BLOCKS) {
        int lane = threadIdx.x & 63;
        int probe = labels[2 * lane + 1];           // odd words of first 64 pairs
        bool is64 = (__ballot(probe != 0) == 0ull); // all-zero => int64 layout
        int i = b * 256 + threadIdx.x;              // VQ block index
        int lab = is64 ? labels[2 * i] : labels[i];
        int kb = i & 511;                           // k-block within row
        f32x4 c0 = ((const f32x4*)centroids)[2 * lab];
        f32x4 c1 = ((const f32x4*)centroids)[2 * lab + 1];
        f32x4 s0 = ((const f32x4*)scale)[2 * kb];
        f32x4 s1 = ((const f32x4*)scale)[2 * kb + 1];
        bf16x8 o;
#pragma unroll
        for (int j = 0; j < 4; ++j) {
            o[j]     = (short)f2bf(c0[j] * s0[j]);
            o[4 + j] = (short)f2bf(c1[j] * s1[j]);
        }
        ((bf16x8*)Ws)[i] = o;
    } else {
        int i = (b - VQ_BLOCKS) * 256 + threadIdx.x;
        f32x4 a = ((const f32x4*)x)[2 * i];
        f32x4 c = ((const f32x4*)x)[2 * i + 1];
        bf16x8 o;
#pragma unroll
        for (int j = 0; j < 4; ++j) { o[j] = (short)f2bf(a[j]); o[4 + j] = (short)f2bf(c[j]); }
        ((bf16x8*)Xb)[i] = o;
    }
}

// ---------------------------------------------------------------------------
// Producer/consumer bf16 GEMM, C = A @ Ws^T + bias (fp32 out).
// 512 threads: waves 0-3 consume (64x64 quadrants, 4x4 mfma_16x16x32_bf16),
// waves 4-7 each produce one slot of a 4-deep LDS ring (16KB/stage).
// No __syncthreads in the K-loop: producers publish via LDS release stores
// after draining ONLY their own global_load_lds (s_waitcnt vmcnt(0) is
// per-wave); consumers acquire-spin on ready[], release done[] after reads.
// XOR bank-swizzle from R3 retained (slot c lives at c ^ ((row>>1)&3)).
// ---------------------------------------------------------------------------
__global__ __launch_bounds__(512, 4)
void gemm_bias(const u16* __restrict__ A, const u16* __restrict__ B,
               const float* __restrict__ bias, float* __restrict__ C) {
    __shared__ u16 buf[DEPTH * 8192];   // stage: A 4096 u16 (128x32) + B 4096
    __shared__ int ready[DEPTH];
    __shared__ int done[DEPTH];

    const int tid  = threadIdx.x;
    const int wave = tid >> 6;
    const int lane = tid & 63;
    const int bm = blockIdx.y * 128;
    const int bn = blockIdx.x * 128;

    if (tid < DEPTH) done[tid] = 0;
    else if (tid < 2 * DEPTH) ready[tid - DEPTH] = 0;
    __syncthreads();                    // the only barrier in this kernel

    if (wave >= 4) {
        // ---------------- producer: wave owns ring stage s ----------------
        const int s = wave - 4;
        u16* stA = buf + s * 8192;
        u16* stB = stA + 4096;
        // lane covers row (lane>>2) of a 16-row chunk, physical slot lane&3;
        // source colblock = slot ^ ((R>>1)&3) = (lane&3) ^ ((lane>>3)&3).
        const int prow = lane >> 2;
        const int scol = (((lane & 3) ^ ((lane >> 3) & 3))) * 8;
        const u16* baseA = A + (size_t)(bm + prow) * K_DIM + scol;
        const u16* baseB = B + (size_t)(bn + prow) * K_DIM + scol;

        for (int r = 0; r < ROUNDS; ++r) {
            const int kt = r * DEPTH + s;
            while (__hip_atomic_load(&done[s], __ATOMIC_ACQUIRE,
                                     __HIP_MEMORY_SCOPE_WORKGROUP) < 4 * r)
                __builtin_amdgcn_s_sleep(1);
            const u16* gA = baseA + kt * 32;
            const u16* gB = baseB + kt * 32;
#pragma unroll
            for (int j = 0; j < 8; ++j)
                __builtin_amdgcn_global_load_lds(
                    (const AS1 void*)(gA + (size_t)(16 * j) * K_DIM),
                    (AS3 void*)(stA + j * 512), 16, 0, 0);
#pragma unroll
            for (int j = 0; j < 8; ++j)
                __builtin_amdgcn_global_load_lds(
                    (const AS1 void*)(gB + (size_t)(16 * j) * K_DIM),
                    (AS3 void*)(stB + j * 512), 16, 0, 0);
            asm volatile("s_waitcnt vmcnt(0)" ::: "memory");  // own loads only
            __hip_atomic_store(&ready[s], r + 1, __ATOMIC_RELEASE,
                               __HIP_MEMORY_SCOPE_WORKGROUP);
        }
        return;
    }

    // ------------------- consumer: wave quadrant (wm, wn) -------------------
    const int wm = (wave >> 1) * 64;
    const int wn = (wave & 1) * 64;
    const int fm = lane & 15;
    const int fks = (((lane >> 4) ^ ((lane >> 1) & 3)) & 3) * 8;  // swizzled slot

    f32x4 acc[4][4];
#pragma unroll
    for (int i = 0; i < 4; ++i)
#pragma unroll
        for (int j = 0; j < 4; ++j)
            acc[i][j] = (f32x4){0.f, 0.f, 0.f, 0.f};

    for (int kt = 0; kt < TILES; ++kt) {
        const int s = kt & (DEPTH - 1);
        const int r = kt >> 2;
        while (__hip_atomic_load(&ready[s], __ATOMIC_ACQUIRE,
                                 __HIP_MEMORY_SCOPE_WORKGROUP) < r + 1)
            __builtin_amdgcn_s_sleep(1);
        const u16* stA = buf + s * 8192;
        const u16* stB = stA + 4096;

        bf16x8 af[4], bfr[4];
#pragma unroll
        for (int i = 0; i < 4; ++i)
            af[i] = *(const bf16x8*)&stA[(wm + i * 16 + fm) * 32 + fks];
#pragma unroll
        for (int j = 0; j < 4; ++j)
            bfr[j] = *(const bf16x8*)&stB[(wn + j * 16 + fm) * 32 + fks];

        // unblock the producer ASAP: release orders the ds_reads before it
        if (lane == 0)
            __hip_atomic_fetch_add(&done[s], 1, __ATOMIC_RELEASE,
                                   __HIP_MEMORY_SCOPE_WORKGROUP);

#pragma unroll
        for (int i = 0; i < 4; ++i)
#pragma unroll
            for (int j = 0; j < 4; ++j)
                acc[i][j] = __builtin_amdgcn_mfma_f32_16x16x32_bf16(
                    af[i], bfr[j], acc[i][j], 0, 0, 0);
    }

    float biasv[4];
#pragma unroll
    for (int j = 0; j < 4; ++j)
        biasv[j] = bias[bn + wn + j * 16 + (lane & 15)];

    const int crow0 = bm + wm + (lane >> 4) * 4;
    const int ccol0 = bn + wn + (lane & 15);
#pragma unroll
    for (int i = 0; i < 4; ++i)
#pragma unroll
        for (int r = 0; r < 4; ++r) {
            size_t rowoff = (size_t)(crow0 + i * 16 + r) * N_DIM;
#pragma unroll
            for (int j = 0; j < 4; ++j)
                C[rowoff + ccol0 + j * 16] = acc[i][j][r] + biasv[j];
        }
}

extern "C" void kernel_launch(void* const* d_in, const int* in_sizes, int n_in,
                              void* d_out, int out_size, void* d_ws, size_t ws_size,
                              hipStream_t stream) {
    const float* x         = (const float*)d_in[0];   // [4,2048,4096] fp32
    const float* centroids = (const float*)d_in[1];   // [256,8] fp32
    const int*   labels    = (const int*)d_in[2];     // [2M] int32/64
    const float* scale     = (const float*)d_in[3];   // [4096] fp32
    const float* bias      = (const float*)d_in[4];   // [4096] fp32
    float* out             = (float*)d_out;           // [4,2048,4096] fp32

    u16* Ws = (u16*)d_ws;                              // 32 MB
    u16* Xb = (u16*)((char*)d_ws + (size_t)NUM_VQ * 16); // 64 MB

    prep<<<VQ_BLOCKS + CVT_BLOCKS, 256, 0, stream>>>(labels, centroids, scale, x,
                                                     Ws, Xb);

    dim3 grid(N_DIM / 128, M_DIM / 128);
    gemm_bias<<<grid, 512, 0, stream>>>(Xb, Ws, bias, out);
}

// Round 2
// 520.885 us; speedup vs baseline: 1.0267x; 1.0267x over previous
//
#include <hip/hip_runtime.h>
#include <stdint.h>

#define M_DIM 8192
#define N_DIM 4096
#define K_DIM 4096
#define NUM_VQ (N_DIM * K_DIM / 8)     // 2,097,152 VQ blocks
#define NUM_X  (M_DIM * K_DIM)         // 33,554,432 x elements
#define VQ_BLOCKS (NUM_VQ / 256)       // 8192
#define CVT_BLOCKS (NUM_X / 8 / 256)   // 16384

#define BK     64                      // K per ring stage
#define DEPTH  2                       // LDS ring stages
#define TILES  (K_DIM / BK)            // 64
#define ROUNDS (TILES / DEPTH)         // 32

#define AS1 __attribute__((address_space(1)))
#define AS3 __attribute__((address_space(3)))

typedef __attribute__((ext_vector_type(4))) float f32x4;
typedef __attribute__((ext_vector_type(8))) short bf16x8;
typedef unsigned short u16;

__device__ inline unsigned short f2bf(float f) {
    union { float f; unsigned int i; } v; v.f = f;
    unsigned int x = v.i;
    return (unsigned short)((x + 0x7FFFu + ((x >> 16) & 1u)) >> 16);  // RNE
}

// ---------------------------------------------------------------------------
// prep_w: VQ decompress + fold scale -> bf16 Ws. (split from old prep for
// rocprof observability; math identical)
// ---------------------------------------------------------------------------
__global__ void prep_w(const int* __restrict__ labels,
                       const float* __restrict__ centroids,
                       const float* __restrict__ scale,
                       u16* __restrict__ Ws) {
    int lane = threadIdx.x & 63;
    int probe = labels[2 * lane + 1];           // odd words of first 64 pairs
    bool is64 = (__ballot(probe != 0) == 0ull); // all-zero => int64 layout
    int i = blockIdx.x * 256 + threadIdx.x;     // VQ block index
    int lab = is64 ? labels[2 * i] : labels[i];
    int kb = i & 511;                           // k-block within row
    f32x4 c0 = ((const f32x4*)centroids)[2 * lab];
    f32x4 c1 = ((const f32x4*)centroids)[2 * lab + 1];
    f32x4 s0 = ((const f32x4*)scale)[2 * kb];
    f32x4 s1 = ((const f32x4*)scale)[2 * kb + 1];
    bf16x8 o;
#pragma unroll
    for (int j = 0; j < 4; ++j) {
        o[j]     = (short)f2bf(c0[j] * s0[j]);
        o[4 + j] = (short)f2bf(c1[j] * s1[j]);
    }
    ((bf16x8*)Ws)[i] = o;
}

// ---------------------------------------------------------------------------
// prep_x: fp32 x -> bf16 Xb.
// ---------------------------------------------------------------------------
__global__ void prep_x(const float* __restrict__ x, u16* __restrict__ Xb) {
    int i = blockIdx.x * 256 + threadIdx.x;
    f32x4 a = ((const f32x4*)x)[2 * i];
    f32x4 c = ((const f32x4*)x)[2 * i + 1];
    bf16x8 o;
#pragma unroll
    for (int j = 0; j < 4; ++j) { o[j] = (short)f2bf(a[j]); o[4 + j] = (short)f2bf(c[j]); }
    ((bf16x8*)Xb)[i] = o;
}

// ---------------------------------------------------------------------------
// Producer/consumer bf16 GEMM, C = A @ Ws^T + bias (fp32 out).
// R5: BK 32->64 per ring stage (32 MFMA + 16 ds_read_b128 per tile-visit,
// halves sync events per MFMA), DEPTH 4->2 (same 64KB LDS, 2 blocks/CU).
// 384 threads: waves 0-3 consume (64x64 quadrants, 4x4 mfma_16x16x32_bf16
// over two K=32 slices), waves 4-5 each produce one ring stage (32KB:
// A[128][64] + B[128][64] bf16).
// Swizzle for 128B rows: logical chunk c (16B) of row R lives at physical
// chunk c ^ (R&7). Producer: LDS dest linear (global_load_lds lane x 16B),
// source col pre-swizzled: scol = ((lane&7) ^ (lane>>3)) * 8 -- lane-constant.
// Consumer read: phys = (kk*4 + (lane>>4)) ^ (lane&7). Conflict-free: each
// 4-bank group serves exactly 8 lanes x 16B = minimum service time.
// Sync machinery identical to R4 (per-wave vmcnt(0) publish, acquire spins).
// ---------------------------------------------------------------------------
__global__ __launch_bounds__(384, 3)
void gemm_bias(const u16* __restrict__ A, const u16* __restrict__ B,
               const float* __restrict__ bias, float* __restrict__ C) {
    __shared__ u16 buf[DEPTH * 16384];  // stage: A 8192 u16 (128x64) + B 8192
    __shared__ int ready[DEPTH];
    __shared__ int done[DEPTH];

    const int tid  = threadIdx.x;
    const int wave = tid >> 6;
    const int lane = tid & 63;
    const int bm = blockIdx.y * 128;
    const int bn = blockIdx.x * 128;

    if (tid < DEPTH) done[tid] = 0;
    else if (tid < 2 * DEPTH) ready[tid - DEPTH] = 0;
    __syncthreads();                    // the only barrier in this kernel

    if (wave >= 4) {
        // ---------------- producer: wave owns ring stage s ----------------
        const int s = wave - 4;
        u16* stA = buf + s * 16384;
        u16* stB = stA + 8192;
        // one global_load_lds covers 8 rows x 8 chunks (1KB LDS linear).
        // lane -> (row = j*8 + (lane>>3), phys chunk = lane&7); source
        // chunk = phys ^ (row&7) = (lane&7) ^ (lane>>3): lane-constant.
        const int prow = lane >> 3;                  // 0..7
        const int scol = ((lane & 7) ^ prow) * 8;    // pre-swizzled col
        const u16* baseA = A + (size_t)(bm + prow) * K_DIM + scol;
        const u16* baseB = B + (size_t)(bn + prow) * K_DIM + scol;

        for (int r = 0; r < ROUNDS; ++r) {
            const int kt = r * DEPTH + s;
            while (__hip_atomic_load(&done[s], __ATOMIC_ACQUIRE,
                                     __HIP_MEMORY_SCOPE_WORKGROUP) < 4 * r)
                __builtin_amdgcn_s_sleep(1);
            const u16* gA = baseA + kt * BK;
            const u16* gB = baseB + kt * BK;
#pragma unroll
            for (int j = 0; j < 16; ++j)
                __builtin_amdgcn_global_load_lds(
                    (const AS1 void*)(gA + (size_t)(8 * j) * K_DIM),
                    (AS3 void*)(stA + j * 512), 16, 0, 0);
#pragma unroll
            for (int j = 0; j < 16; ++j)
                __builtin_amdgcn_global_load_lds(
                    (const AS1 void*)(gB + (size_t)(8 * j) * K_DIM),
                    (AS3 void*)(stB + j * 512), 16, 0, 0);
            asm volatile("s_waitcnt vmcnt(0)" ::: "memory");  // own loads only
            __hip_atomic_store(&ready[s], r + 1, __ATOMIC_RELEASE,
                               __HIP_MEMORY_SCOPE_WORKGROUP);
        }
        return;
    }

    // ------------------- consumer: wave quadrant (wm, wn) -------------------
    const int wm = (wave >> 1) * 64;
    const int wn = (wave & 1) * 64;
    const int fm = lane & 15;
    // physical 8-col chunk (u16 offset in a 64-elem row) for kk = 0,1
    const int pc0 = (((lane >> 4)    ) ^ (lane & 7)) * 8;
    const int pc1 = (((lane >> 4) | 4) ^ (lane & 7)) * 8;

    f32x4 acc[4][4];
#pragma unroll
    for (int i = 0; i < 4; ++i)
#pragma unroll
        for (int j = 0; j < 4; ++j)
            acc[i][j] = (f32x4){0.f, 0.f, 0.f, 0.f};

    for (int kt = 0; kt < TILES; ++kt) {
        const int s = kt & (DEPTH - 1);
        const int r = kt >> 1;
        while (__hip_atomic_load(&ready[s], __ATOMIC_ACQUIRE,
                                 __HIP_MEMORY_SCOPE_WORKGROUP) < r + 1)
            __builtin_amdgcn_s_sleep(1);
        const u16* stA = buf + s * 16384;
        const u16* stB = stA + 8192;

        bf16x8 a0[4], b0[4], a1[4], b1[4];
#pragma unroll
        for (int i = 0; i < 4; ++i) {
            a0[i] = *(const bf16x8*)&stA[(wm + i * 16 + fm) * 64 + pc0];
            a1[i] = *(const bf16x8*)&stA[(wm + i * 16 + fm) * 64 + pc1];
        }
#pragma unroll
        for (int j = 0; j < 4; ++j) {
            b0[j] = *(const bf16x8*)&stB[(wn + j * 16 + fm) * 64 + pc0];
            b1[j] = *(const bf16x8*)&stB[(wn + j * 16 + fm) * 64 + pc1];
        }

        // unblock the producer ASAP: release orders the ds_reads before it
        if (lane == 0)
            __hip_atomic_fetch_add(&done[s], 1, __ATOMIC_RELEASE,
                                   __HIP_MEMORY_SCOPE_WORKGROUP);

#pragma unroll
        for (int i = 0; i < 4; ++i)
#pragma unroll
            for (int j = 0; j < 4; ++j) {
                acc[i][j] = __builtin_amdgcn_mfma_f32_16x16x32_bf16(
                    a0[i], b0[j], acc[i][j], 0, 0, 0);
                acc[i][j] = __builtin_amdgcn_mfma_f32_16x16x32_bf16(
                    a1[i], b1[j], acc[i][j], 0, 0, 0);
            }
    }

    float biasv[4];
#pragma unroll
    for (int j = 0; j < 4; ++j)
        biasv[j] = bias[bn + wn + j * 16 + (lane & 15)];

    const int crow0 = bm + wm + (lane >> 4) * 4;
    const int ccol0 = bn + wn + (lane & 15);
#pragma unroll
    for (int i = 0; i < 4; ++i)
#pragma unroll
        for (int r = 0; r < 4; ++r) {
            size_t rowoff = (size_t)(crow0 + i * 16 + r) * N_DIM;
#pragma unroll
            for (int j = 0; j < 4; ++j)
                C[rowoff + ccol0 + j * 16] = acc[i][j][r] + biasv[j];
        }
}

extern "C" void kernel_launch(void* const* d_in, const int* in_sizes, int n_in,
                              void* d_out, int out_size, void* d_ws, size_t ws_size,
                              hipStream_t stream) {
    const float* x         = (const float*)d_in[0];   // [4,2048,4096] fp32
    const float* centroids = (const float*)d_in[1];   // [256,8] fp32
    const int*   labels    = (const int*)d_in[2];     // [2M] int32/64
    const float* scale     = (const float*)d_in[3];   // [4096] fp32
    const float* bias      = (const float*)d_in[4];   // [4096] fp32
    float* out             = (float*)d_out;           // [4,2048,4096] fp32

    u16* Ws = (u16*)d_ws;                              // 32 MB
    u16* Xb = (u16*)((char*)d_ws + (size_t)NUM_VQ * 16); // 64 MB

    prep_w<<<VQ_BLOCKS, 256, 0, stream>>>(labels, centroids, scale, Ws);
    prep_x<<<CVT_BLOCKS, 256, 0, stream>>>(x, Xb);

    dim3 grid(N_DIM / 128, M_DIM / 128);
    gemm_bias<<<grid, 384, 0, stream>>>(Xb, Ws, bias, out);
}